// Round 5
// baseline (279.236 us; speedup 1.0000x reference)
//
#include <hip/hip_runtime.h>

typedef unsigned short u16;
typedef unsigned int u32;
typedef short bf16x8 __attribute__((ext_vector_type(8)));
typedef float f32x4 __attribute__((ext_vector_type(4)));
typedef u32 u32x4 __attribute__((ext_vector_type(4)));

#define AS_GLOBAL __attribute__((address_space(1)))
#define AS_LDS __attribute__((address_space(3)))

__device__ __forceinline__ void async16(const void* g, void* l) {
  __builtin_amdgcn_global_load_lds((const AS_GLOBAL u32*)g, (AS_LDS u32*)l, 16, 0, 0);
}

__device__ __forceinline__ u16 f2bf(float f) {
  u32 u = __builtin_bit_cast(u32, f);
  u += 0x7FFFu + ((u >> 16) & 1u);   // RNE
  return (u16)(u >> 16);
}

__device__ __forceinline__ u32 pk2bf(float lo, float hi) {
  return __builtin_amdgcn_perm(__builtin_bit_cast(u32, hi),
                               __builtin_bit_cast(u32, lo), 0x07060302u);
}

__device__ __forceinline__ float fexp2(float x) {
#if __has_builtin(__builtin_amdgcn_exp2f)
  return __builtin_amdgcn_exp2f(x);
#else
  return exp2f(x);
#endif
}

// ---------------- Pass A: all four f32 -> bf16 converts in one launch ----------------
__global__ __launch_bounds__(256) void cvt_all(const float* __restrict__ x,
                                               const float* __restrict__ wq,
                                               const float* __restrict__ wk,
                                               const float* __restrict__ wv,
                                               u16* __restrict__ xb,
                                               u16* __restrict__ wb) {
  const int blk = blockIdx.x;
  const float* src;
  u16* dst;
  int i;
  if (blk < 8192) {
    src = x; dst = xb; i = blk * 256 + threadIdx.x;
  } else if (blk < 9216) {
    src = wq; dst = wb; i = (blk - 8192) * 256 + threadIdx.x;
  } else if (blk < 10240) {
    src = wk; dst = wb + 1048576; i = (blk - 9216) * 256 + threadIdx.x;
  } else {
    src = wv; dst = wb + 2097152; i = (blk - 10240) * 256 + threadIdx.x;
  }
  float4 f = reinterpret_cast<const float4*>(src)[i];
  ushort4 o;
  o.x = f2bf(f.x); o.y = f2bf(f.y); o.z = f2bf(f.z); o.w = f2bf(f.w);
  reinterpret_cast<ushort4*>(dst)[i] = o;
}

// ---------------- Pass B: QKV projection GEMM (C = X * W^T) ----------------
// Round-5 (= round-4 resubmit, isolated): round-1 skeleton (256 thr, 2x2
// waves of 64x64) with a DEEP DMA pipeline instead of 1-tile-deep dbuf:
//   - BK=32, FOUR LDS buffers (4 x (8+8) KB = 64 KB -> 2 blocks/CU).
//   - Prefetch distance 3 tiles (~2400+ cy landing window vs ~600 before;
//     L2/L3-hit latency ~600-900 cy was stalling every iteration).
//   - Counted wait: asm vmcnt(8) retires ONLY the tile about to be consumed
//     (per-wave FIFO: 8 newest outstanding = tiles t+1,t+2 stay in flight
//     across the barrier). Raw s_barrier (no vmcnt(0) drain).
//   - Race-free: stage(t+3) issued AFTER the barrier of iter t; every wave's
//     reads of tile t-1 (same buffer) completed into registers before its
//     barrier arrival (compiler lgkmcnt before MFMA use), and each wave
//     waited vmcnt for its own tile-t loads before the barrier.
//   - Swizzle (2-way, free): LDS position p of row r holds chunk p^((r>>1)&3);
//     staging pre-swizzles the GLOBAL source; reads use quad^((lq>>1)&3).
//   - XCD-contiguous remap: each XCD owns 192 consecutive logical blocks =
//     3 (n,z) W-panels (768 KB, L2-resident).
// grid: x = m-tile (64), y = n-tile (8), z = matrix (3)
// z=0 (Q), z=1 (K): out [B][H][T][64]; z=2 (V): out TRANSPOSED [B][H][64][T]
__global__ __launch_bounds__(256, 2) void qkv_gemm(const u16* __restrict__ X,
                                                   const u16* __restrict__ W,
                                                   u16* __restrict__ O) {
  // XCD-aware bijective remap of the 1536-block grid (8 XCDs round-robin on
  // dispatch id): XCD j runs logical ids j*192..j*192+191.
  const int orig = blockIdx.x + 64 * (blockIdx.y + (blockIdx.z << 3));
  const int l = (orig & 7) * 192 + (orig >> 3);
  const int bx = l & 63;
  const int by = (l >> 6) & 7;
  const int bz = l >> 9;

  const u16* Wz = W + (size_t)bz * (1024 * 1024);
  u16* Oz = O + (size_t)bz * (8192 * 1024);

  __shared__ __align__(16) u16 As[4][128 * 32];   // 8 KB per buffer
  __shared__ __align__(16) u16 Bs[4][128 * 32];

  const int t = threadIdx.x;
  const int lane = t & 63, w = t >> 6, quad = lane >> 4, lq = lane & 15;
  const int wm = (w >> 1) * 64, wn = (w & 1) * 64;
  const int swr = (lq >> 1) & 3;                  // read-side swizzle
  const size_t m0 = (size_t)bx * 128;
  const int n0 = by * 128;

  // staging source offsets (u16 units): slot s -> row s>>2, position s&3,
  // pre-swizzled source chunk = (s&3) ^ ((row>>1)&3)
  int off[2];
#pragma unroll
  for (int j = 0; j < 2; ++j) {
    const int s = j * 256 + t, row = s >> 2, c = (s & 3) ^ ((row >> 1) & 3);
    off[j] = row * 1024 + c * 8;
  }
  const u16* gA = X + m0 * 1024;
  const u16* gB = Wz + (size_t)n0 * 1024;

  f32x4 acc[4][4];
#pragma unroll
  for (int i = 0; i < 4; ++i)
#pragma unroll
    for (int j = 0; j < 4; ++j) acc[i][j] = f32x4{0.f, 0.f, 0.f, 0.f};

  // 4 gload_lds(16B)/thread stages one 128x32 A panel + 128x32 B panel
  auto stage = [&](int kt, int nb) {
    const u16* ga = gA + kt * 32;
    const u16* gb = gB + kt * 32;
    async16(ga + off[0], &As[nb][t * 8]);
    async16(ga + off[1], &As[nb][(256 + t) * 8]);
    async16(gb + off[0], &Bs[nb][t * 8]);
    async16(gb + off[1], &Bs[nb][(256 + t) * 8]);
  };

  auto compute_tile = [&](int cur) {
    bf16x8 Af[4], Bf[4];
#pragma unroll
    for (int i = 0; i < 4; ++i) {
      Af[i] = *reinterpret_cast<const bf16x8*>(
          &As[cur][(wm + i * 16 + lq) * 32 + (quad ^ swr) * 8]);
      Bf[i] = *reinterpret_cast<const bf16x8*>(
          &Bs[cur][(wn + i * 16 + lq) * 32 + (quad ^ swr) * 8]);
    }
#pragma unroll
    for (int i = 0; i < 4; ++i)
#pragma unroll
      for (int j = 0; j < 4; ++j)
        acc[i][j] = __builtin_amdgcn_mfma_f32_16x16x32_bf16(Af[i], Bf[j], acc[i][j], 0, 0, 0);
  };

  // prologue: 3 tiles in flight
  stage(0, 0);
  stage(1, 1);
  stage(2, 2);

  for (int kt = 0; kt < 30; ++kt) {
    // retire tile kt (8 newest outstanding = tiles kt+1, kt+2 stay in flight)
    asm volatile("s_waitcnt vmcnt(8)" ::: "memory");
    __builtin_amdgcn_s_barrier();
    __builtin_amdgcn_sched_barrier(0);
    if (kt < 29) stage(kt + 3, (kt + 3) & 3);
    compute_tile(kt & 3);
  }
  // kt = 30: tiles 30,31 outstanding (8) -> retire 30
  asm volatile("s_waitcnt vmcnt(4)" ::: "memory");
  __builtin_amdgcn_s_barrier();
  __builtin_amdgcn_sched_barrier(0);
  compute_tile(2);
  // kt = 31
  asm volatile("s_waitcnt vmcnt(0)" ::: "memory");
  __builtin_amdgcn_s_barrier();
  __builtin_amdgcn_sched_barrier(0);
  compute_tile(3);

  // epilogue: C[m][n], m = m0+wm+i*16+quad*4+r, n = n0+wn+j*16+lq
#pragma unroll
  for (int i = 0; i < 4; ++i) {
#pragma unroll
    for (int j = 0; j < 4; ++j) {
      const int n = n0 + wn + j * 16 + lq;
      const int hh = n >> 6, d = n & 63;
#pragma unroll
      for (int r = 0; r < 4; ++r) {
        const size_t m = m0 + wm + i * 16 + quad * 4 + r;
        const size_t bb = m >> 11, tt = m & 2047;
        if (bz != 2)
          Oz[((bb * 16 + hh) * 2048 + tt) * 64 + d] = f2bf(acc[i][j][r]);
        else
          Oz[((bb * 16 + hh) * 64 + d) * 2048 + tt] = f2bf(acc[i][j][r]);
      }
    }
  }
}

// ---------------- Pass C: flash attention, S^T-form, full-rate 16x16x32 PV ----------------
// ROUND-3 PROVEN VERSION, UNCHANGED (3 passing benches). Double-buffered
// __syncthreads pipeline; deep-pipeline conversion deferred until the qkv
// experiment has a clean measurement (isolate one experiment per round).
//
// grid: x = b*16+h (64), y = q-tile (8). Block = 4 waves, 64 q/wave.
// Key-permuted S^T: for the 32-key half `half`, sub-MFMA kg2 in {0,1} reads K row
//   key(m) = half*32 + (m>>2)*8 + kg2*4 + (m&3)   (m = A-frag row = lq)
// so the S^T C-output gives each lane its 8 P values at keys quad*8+{0..7} ==
// the 16x16x32 A-frag layout. PV runs at full 2xK MFMA rate; V B-frag is one
// contiguous bf16x8 per dg. Row-sum via mfma(pa, ones, Lacc): C reg r = lsum
// for q = qg*16+quad*4+r (same layout as O rows, no cross-lane reduce).
// LDS swizzle: position = chunk ^ s(row), s(row) = (row&3) | (((row>>3)&1)<<2).
__global__ __launch_bounds__(256, 2) void palace_attn(const u16* __restrict__ Q,
                                                      const u16* __restrict__ K,
                                                      const u16* __restrict__ Vt,
                                                      float* __restrict__ out,
                                                      const float* __restrict__ wptr) {
  const int bh = blockIdx.x, qt = blockIdx.y;
  const int h = bh & 15, b = bh >> 4;
  const size_t base = (size_t)bh * (2048 * 64);

  __shared__ __align__(16) u16 Ks[2][64 * 64];   // [key][d], swizzled 16B chunks
  __shared__ __align__(16) u16 Vs[2][64 * 64];   // [d][key], swizzled 16B chunks

  const int t = threadIdx.x;
  const int w = t >> 6, lane = t & 63, quad = lane >> 4, lq = lane & 15;
  const int lq3 = lq >> 3;
  const int swk = (lq & 3) | (((lq >> 2) & 1) << 2);  // s(row) for permuted K rows
  const int swv = (lq & 3) | (lq3 << 2);              // s(d) for V rows d=dg*16+lq
  const float sig = 1.f / (1.f + __expf(-wptr[0]));
  const float Ci = 0.125f * 1.44269504f;   // intra coeff (scale * log2 e)
  const float Co = Ci * sig;               // inter coeff
  const float MC = 14.4269504f;            // fixed softmax offset: 10 * log2 e

  // palace mask: q block (mod 64) = qg*2+lq3; key block = half*4+quad (uniform
  // over all 8 keys a lane owns, thanks to the key permutation).
  float cft[2][4];
#pragma unroll
  for (int half = 0; half < 2; ++half)
#pragma unroll
    for (int qg = 0; qg < 4; ++qg)
      cft[half][qg] = (half * 4 + quad == qg * 2 + lq3) ? Ci : Co;

  // Q B-frags (16x16x32): B[k=d][n=q]
  bf16x8 qf[4][2];
#pragma unroll
  for (int qg = 0; qg < 4; ++qg)
#pragma unroll
    for (int kc = 0; kc < 2; ++kc)
      qf[qg][kc] = *reinterpret_cast<const bf16x8*>(
          Q + base + (size_t)(qt * 256 + w * 64 + qg * 16 + lq) * 64 + kc * 32 + quad * 8);

  // staging: slot = r*256+t; row = slot>>3; source chunk = (slot&7) ^ s(row)
  int ko[2], vo[2];
#pragma unroll
  for (int r = 0; r < 2; ++r) {
    const int slot = r * 256 + t;
    const int row = slot >> 3;
    const int sr = (row & 3) | (((row >> 3) & 1) << 2);
    const int cl = (slot & 7) ^ sr;
    ko[r] = row * 64 + cl * 8;     // K: [key][64]
    vo[r] = row * 2048 + cl * 8;   // Vt: [d][2048]
  }

  f32x4 O[4][4];
  f32x4 Lacc[4];
#pragma unroll
  for (int qg = 0; qg < 4; ++qg) {
    Lacc[qg] = f32x4{0.f, 0.f, 0.f, 0.f};
#pragma unroll
    for (int dg = 0; dg < 4; ++dg) O[qg][dg] = f32x4{0.f, 0.f, 0.f, 0.f};
  }

  const short oneb = (short)0x3F80;  // bf16 1.0
  const bf16x8 ones8 = {oneb, oneb, oneb, oneb, oneb, oneb, oneb, oneb};

  // prologue: stage tile 0 into buffer 0
  {
    const u16* kgp = K + base;
    const u16* vgp = Vt + base;
    async16(kgp + ko[0], &Ks[0][(w * 64) * 8]);
    async16(kgp + ko[1], &Ks[0][(256 + w * 64) * 8]);
    async16(vgp + vo[0], &Vs[0][(w * 64) * 8]);
    async16(vgp + vo[1], &Vs[0][(256 + w * 64) * 8]);
  }

  for (int kt = 0; kt < 32; ++kt) {
    const int cur = kt & 1;
    __syncthreads();  // drains DMA into buf[cur]; prior reads of buf[cur^1] done
    if (kt < 31) {
      const u16* kgp = K + base + (size_t)(kt + 1) * 4096;
      const u16* vgp = Vt + base + (size_t)(kt + 1) * 64;
      const int nb = cur ^ 1;
      async16(kgp + ko[0], &Ks[nb][(w * 64) * 8]);
      async16(kgp + ko[1], &Ks[nb][(256 + w * 64) * 8]);
      async16(vgp + vo[0], &Vs[nb][(w * 64) * 8]);
      async16(vgp + vo[1], &Vs[nb][(256 + w * 64) * 8]);
    }

#pragma unroll
    for (int half = 0; half < 2; ++half) {
      // permuted K rows: key = half*32 + (lq>>2)*8 + kg2*4 + (lq&3)
      const int rb = half * 32 + ((lq >> 2) << 3) + (lq & 3);
      bf16x8 kf[2][2];
#pragma unroll
      for (int kg2 = 0; kg2 < 2; ++kg2) {
        const int krow = rb + kg2 * 4;
        kf[kg2][0] = *reinterpret_cast<const bf16x8*>(
            &Ks[cur][krow * 64 + (quad ^ swk) * 8]);          // d chunk = quad
        kf[kg2][1] = *reinterpret_cast<const bf16x8*>(
            &Ks[cur][krow * 64 + ((quad + 4) ^ swk) * 8]);    // d chunk = quad+4
      }

      // V B-frags (16x16x32): B[k=key][n=d], keys half*32+quad*8..+7 contiguous
      bf16x8 vbf[4];
#pragma unroll
      for (int dg = 0; dg < 4; ++dg)
        vbf[dg] = *reinterpret_cast<const bf16x8*>(
            &Vs[cur][(dg * 16 + lq) * 64 + ((half * 4 + quad) ^ swv) * 8]);

#pragma unroll
      for (int qg = 0; qg < 4; ++qg) {
        // S^T[key][q] for the 32-key half: two sub-MFMAs x two d-chunks
        f32x4 z0 = {0.f, 0.f, 0.f, 0.f}, z1 = {0.f, 0.f, 0.f, 0.f};
        z0 = __builtin_amdgcn_mfma_f32_16x16x32_bf16(kf[0][0], qf[qg][0], z0, 0, 0, 0);
        z0 = __builtin_amdgcn_mfma_f32_16x16x32_bf16(kf[0][1], qf[qg][1], z0, 0, 0, 0);
        z1 = __builtin_amdgcn_mfma_f32_16x16x32_bf16(kf[1][0], qf[qg][0], z1, 0, 0, 0);
        z1 = __builtin_amdgcn_mfma_f32_16x16x32_bf16(kf[1][1], qf[qg][1], z1, 0, 0, 0);

        const float cf = cft[half][qg];
        const float p0 = fexp2(__builtin_fmaf(z0[0], cf, -MC));
        const float p1 = fexp2(__builtin_fmaf(z0[1], cf, -MC));
        const float p2 = fexp2(__builtin_fmaf(z0[2], cf, -MC));
        const float p3 = fexp2(__builtin_fmaf(z0[3], cf, -MC));
        const float p4 = fexp2(__builtin_fmaf(z1[0], cf, -MC));
        const float p5 = fexp2(__builtin_fmaf(z1[1], cf, -MC));
        const float p6 = fexp2(__builtin_fmaf(z1[2], cf, -MC));
        const float p7 = fexp2(__builtin_fmaf(z1[3], cf, -MC));

        u32x4 pk;
        pk.x = pk2bf(p0, p1);
        pk.y = pk2bf(p2, p3);
        pk.z = pk2bf(p4, p5);
        pk.w = pk2bf(p6, p7);
        const bf16x8 pa = __builtin_bit_cast(bf16x8, pk);

        // softmax denominator: C reg r = sum_k P[q=qg*16+quad*4+r][k]
        Lacc[qg] = __builtin_amdgcn_mfma_f32_16x16x32_bf16(pa, ones8, Lacc[qg], 0, 0, 0);
#pragma unroll
        for (int dg = 0; dg < 4; ++dg)
          O[qg][dg] = __builtin_amdgcn_mfma_f32_16x16x32_bf16(pa, vbf[dg], O[qg][dg], 0, 0, 0);
      }
    }
  }

  // epilogue: O C-layout: q = qg*16+quad*4+r (row), d = dg*16+lq (col);
  // Lacc has the matching row layout -- no cross-lane reduce needed.
#pragma unroll
  for (int qg = 0; qg < 4; ++qg) {
#pragma unroll
    for (int r = 0; r < 4; ++r) {
      const float iv = 1.f / Lacc[qg][r];
      const size_t trow = (size_t)(qt * 256 + w * 64 + qg * 16 + quad * 4 + r);
      float* op = out + ((size_t)b * 2048 + trow) * 1024 + h * 64 + lq;
#pragma unroll
      for (int dg = 0; dg < 4; ++dg) op[dg * 16] = O[qg][dg][r] * iv;
    }
  }
}

extern "C" void kernel_launch(void* const* d_in, const int* in_sizes, int n_in,
                              void* d_out, int out_size, void* d_ws, size_t ws_size,
                              hipStream_t stream) {
  (void)in_sizes; (void)n_in; (void)out_size; (void)ws_size;
  const float* x = (const float*)d_in[0];
  const float* Wq = (const float*)d_in[1];
  const float* Wk = (const float*)d_in[2];
  const float* Wv = (const float*)d_in[3];
  const float* wip = (const float*)d_in[4];
  float* out = (float*)d_out;

  u16* xb = (u16*)d_ws;
  u16* wb = xb + 8388608;
  u16* qb = wb + 3145728;
  u16* kb = qb + 8388608;
  u16* vb = kb + 8388608;   // holds V^T [B][H][64][2048]

  cvt_all<<<11264, 256, 0, stream>>>(x, Wq, Wk, Wv, xb, wb);
  qkv_gemm<<<dim3(64, 8, 3), 256, 0, stream>>>(xb, wb, qb);
  palace_attn<<<dim3(64, 8, 1), 256, 0, stream>>>(qb, kb, vb, out, wip);
}

// Round 6
// 249.654 us; speedup vs baseline: 1.1185x; 1.1185x over previous
//
#include <hip/hip_runtime.h>

typedef unsigned short u16;
typedef unsigned int u32;
typedef short bf16x8 __attribute__((ext_vector_type(8)));
typedef float f32x4 __attribute__((ext_vector_type(4)));
typedef u32 u32x4 __attribute__((ext_vector_type(4)));

#define AS_GLOBAL __attribute__((address_space(1)))
#define AS_LDS __attribute__((address_space(3)))

__device__ __forceinline__ void async16(const void* g, void* l) {
  __builtin_amdgcn_global_load_lds((const AS_GLOBAL u32*)g, (AS_LDS u32*)l, 16, 0, 0);
}

__device__ __forceinline__ u16 f2bf(float f) {
  u32 u = __builtin_bit_cast(u32, f);
  u += 0x7FFFu + ((u >> 16) & 1u);   // RNE
  return (u16)(u >> 16);
}

__device__ __forceinline__ u32 pk2bf(float lo, float hi) {
  return __builtin_amdgcn_perm(__builtin_bit_cast(u32, hi),
                               __builtin_bit_cast(u32, lo), 0x07060302u);
}

__device__ __forceinline__ float fexp2(float x) {
#if __has_builtin(__builtin_amdgcn_exp2f)
  return __builtin_amdgcn_exp2f(x);
#else
  return exp2f(x);
#endif
}

// ---------------- Pass A: all four f32 -> bf16 converts in one launch ----------------
__global__ __launch_bounds__(256) void cvt_all(const float* __restrict__ x,
                                               const float* __restrict__ wq,
                                               const float* __restrict__ wk,
                                               const float* __restrict__ wv,
                                               u16* __restrict__ xb,
                                               u16* __restrict__ wb) {
  const int blk = blockIdx.x;
  const float* src;
  u16* dst;
  int i;
  if (blk < 8192) {
    src = x; dst = xb; i = blk * 256 + threadIdx.x;
  } else if (blk < 9216) {
    src = wq; dst = wb; i = (blk - 8192) * 256 + threadIdx.x;
  } else if (blk < 10240) {
    src = wk; dst = wb + 1048576; i = (blk - 9216) * 256 + threadIdx.x;
  } else {
    src = wv; dst = wb + 2097152; i = (blk - 10240) * 256 + threadIdx.x;
  }
  float4 f = reinterpret_cast<const float4*>(src)[i];
  ushort4 o;
  o.x = f2bf(f.x); o.y = f2bf(f.y); o.z = f2bf(f.z); o.w = f2bf(f.w);
  reinterpret_cast<ushort4*>(dst)[i] = o;
}

// ---------------- Pass B: QKV projection GEMM (C = X * W^T) ----------------
// Round-6: deep DMA pipeline (round-5), NATURAL dispatch order (no remap).
// Round-5's XCD-contiguous remap QUADRUPLED HBM fetch (49->200 MB): under
// default round-robin dispatch, all blocks sharing an X panel (same bx) have
// orig == bx (mod 8) -> already same XCD; each XCD reads just 2 MB of X
// (L2-resident, reused 24x) + 6 MB of W. The remap forced every XCD to sweep
// all 16 MB of X three times. DO NOT remap this grid.
// Pipeline (functionally verified in round 5):
//   - BK=32, FOUR LDS buffers (4 x (8+8) KB = 64 KB -> 2 blocks/CU).
//   - Prefetch distance 3 tiles (~2400 cy landing window).
//   - asm vmcnt(8): retire only the tile being consumed; tiles t+1,t+2 stay
//     in flight across the raw s_barrier (no vmcnt(0) drain).
//   - Race-free: stage(t+3) issued AFTER barrier t (all waves' reads of
//     tile t-1 from that buffer are done); per-wave FIFO vmcnt + barrier
//     proves buf[t] fully landed.
//   - Swizzle (2-way, free): LDS position p of row r holds chunk p^((r>>1)&3);
//     staging pre-swizzles the GLOBAL source; reads use quad^((lq>>1)&3).
// grid: x = m-tile (64), y = n-tile (8), z = matrix (3)
// z=0 (Q), z=1 (K): out [B][H][T][64]; z=2 (V): out TRANSPOSED [B][H][64][T]
__global__ __launch_bounds__(256, 2) void qkv_gemm(const u16* __restrict__ X,
                                                   const u16* __restrict__ W,
                                                   u16* __restrict__ O) {
  const int z = blockIdx.z;
  const u16* Wz = W + (size_t)z * (1024 * 1024);
  u16* Oz = O + (size_t)z * (8192 * 1024);

  __shared__ __align__(16) u16 As[4][128 * 32];   // 8 KB per buffer
  __shared__ __align__(16) u16 Bs[4][128 * 32];

  const int t = threadIdx.x;
  const int lane = t & 63, w = t >> 6, quad = lane >> 4, lq = lane & 15;
  const int wm = (w >> 1) * 64, wn = (w & 1) * 64;
  const int swr = (lq >> 1) & 3;                  // read-side swizzle
  const size_t m0 = (size_t)blockIdx.x * 128;
  const int n0 = blockIdx.y * 128;

  // staging source offsets (u16 units): slot s -> row s>>2, position s&3,
  // pre-swizzled source chunk = (s&3) ^ ((row>>1)&3)
  int off[2];
#pragma unroll
  for (int j = 0; j < 2; ++j) {
    const int s = j * 256 + t, row = s >> 2, c = (s & 3) ^ ((row >> 1) & 3);
    off[j] = row * 1024 + c * 8;
  }
  const u16* gA = X + m0 * 1024;
  const u16* gB = Wz + (size_t)n0 * 1024;

  f32x4 acc[4][4];
#pragma unroll
  for (int i = 0; i < 4; ++i)
#pragma unroll
    for (int j = 0; j < 4; ++j) acc[i][j] = f32x4{0.f, 0.f, 0.f, 0.f};

  // 4 gload_lds(16B)/thread stages one 128x32 A panel + 128x32 B panel
  auto stage = [&](int kt, int nb) {
    const u16* ga = gA + kt * 32;
    const u16* gb = gB + kt * 32;
    async16(ga + off[0], &As[nb][t * 8]);
    async16(ga + off[1], &As[nb][(256 + t) * 8]);
    async16(gb + off[0], &Bs[nb][t * 8]);
    async16(gb + off[1], &Bs[nb][(256 + t) * 8]);
  };

  auto compute_tile = [&](int cur) {
    bf16x8 Af[4], Bf[4];
#pragma unroll
    for (int i = 0; i < 4; ++i) {
      Af[i] = *reinterpret_cast<const bf16x8*>(
          &As[cur][(wm + i * 16 + lq) * 32 + (quad ^ swr) * 8]);
      Bf[i] = *reinterpret_cast<const bf16x8*>(
          &Bs[cur][(wn + i * 16 + lq) * 32 + (quad ^ swr) * 8]);
    }
#pragma unroll
    for (int i = 0; i < 4; ++i)
#pragma unroll
      for (int j = 0; j < 4; ++j)
        acc[i][j] = __builtin_amdgcn_mfma_f32_16x16x32_bf16(Af[i], Bf[j], acc[i][j], 0, 0, 0);
  };

  // prologue: 3 tiles in flight
  stage(0, 0);
  stage(1, 1);
  stage(2, 2);

  for (int kt = 0; kt < 30; ++kt) {
    // retire tile kt (8 newest outstanding = tiles kt+1, kt+2 stay in flight)
    asm volatile("s_waitcnt vmcnt(8)" ::: "memory");
    __builtin_amdgcn_s_barrier();
    __builtin_amdgcn_sched_barrier(0);
    if (kt < 29) stage(kt + 3, (kt + 3) & 3);
    compute_tile(kt & 3);
  }
  // kt = 30: tiles 30,31 outstanding (8) -> retire 30
  asm volatile("s_waitcnt vmcnt(4)" ::: "memory");
  __builtin_amdgcn_s_barrier();
  __builtin_amdgcn_sched_barrier(0);
  compute_tile(2);
  // kt = 31
  asm volatile("s_waitcnt vmcnt(0)" ::: "memory");
  __builtin_amdgcn_s_barrier();
  __builtin_amdgcn_sched_barrier(0);
  compute_tile(3);

  // epilogue: C[m][n], m = m0+wm+i*16+quad*4+r, n = n0+wn+j*16+lq
#pragma unroll
  for (int i = 0; i < 4; ++i) {
#pragma unroll
    for (int j = 0; j < 4; ++j) {
      const int n = n0 + wn + j * 16 + lq;
      const int hh = n >> 6, d = n & 63;
#pragma unroll
      for (int r = 0; r < 4; ++r) {
        const size_t m = m0 + wm + i * 16 + quad * 4 + r;
        const size_t bb = m >> 11, tt = m & 2047;
        if (z != 2)
          Oz[((bb * 16 + hh) * 2048 + tt) * 64 + d] = f2bf(acc[i][j][r]);
        else
          Oz[((bb * 16 + hh) * 64 + d) * 2048 + tt] = f2bf(acc[i][j][r]);
      }
    }
  }
}

// ---------------- Pass C: flash attention, S^T-form, full-rate 16x16x32 PV ----------------
// ROUND-3 PROVEN VERSION, UNCHANGED.
// grid: x = b*16+h (64), y = q-tile (8). Block = 4 waves, 64 q/wave.
// Key-permuted S^T: for the 32-key half `half`, sub-MFMA kg2 in {0,1} reads K row
//   key(m) = half*32 + (m>>2)*8 + kg2*4 + (m&3)   (m = A-frag row = lq)
// so the S^T C-output gives each lane its 8 P values at keys quad*8+{0..7} ==
// the 16x16x32 A-frag layout. PV runs at full 2xK MFMA rate; V B-frag is one
// contiguous bf16x8 per dg. Row-sum via mfma(pa, ones, Lacc): C reg r = lsum
// for q = qg*16+quad*4+r (same layout as O rows, no cross-lane reduce).
// LDS swizzle: position = chunk ^ s(row), s(row) = (row&3) | (((row>>3)&1)<<2).
__global__ __launch_bounds__(256, 2) void palace_attn(const u16* __restrict__ Q,
                                                      const u16* __restrict__ K,
                                                      const u16* __restrict__ Vt,
                                                      float* __restrict__ out,
                                                      const float* __restrict__ wptr) {
  const int bh = blockIdx.x, qt = blockIdx.y;
  const int h = bh & 15, b = bh >> 4;
  const size_t base = (size_t)bh * (2048 * 64);

  __shared__ __align__(16) u16 Ks[2][64 * 64];   // [key][d], swizzled 16B chunks
  __shared__ __align__(16) u16 Vs[2][64 * 64];   // [d][key], swizzled 16B chunks

  const int t = threadIdx.x;
  const int w = t >> 6, lane = t & 63, quad = lane >> 4, lq = lane & 15;
  const int lq3 = lq >> 3;
  const int swk = (lq & 3) | (((lq >> 2) & 1) << 2);  // s(row) for permuted K rows
  const int swv = (lq & 3) | (lq3 << 2);              // s(d) for V rows d=dg*16+lq
  const float sig = 1.f / (1.f + __expf(-wptr[0]));
  const float Ci = 0.125f * 1.44269504f;   // intra coeff (scale * log2 e)
  const float Co = Ci * sig;               // inter coeff
  const float MC = 14.4269504f;            // fixed softmax offset: 10 * log2 e

  // palace mask: q block (mod 64) = qg*2+lq3; key block = half*4+quad (uniform
  // over all 8 keys a lane owns, thanks to the key permutation).
  float cft[2][4];
#pragma unroll
  for (int half = 0; half < 2; ++half)
#pragma unroll
    for (int qg = 0; qg < 4; ++qg)
      cft[half][qg] = (half * 4 + quad == qg * 2 + lq3) ? Ci : Co;

  // Q B-frags (16x16x32): B[k=d][n=q]
  bf16x8 qf[4][2];
#pragma unroll
  for (int qg = 0; qg < 4; ++qg)
#pragma unroll
    for (int kc = 0; kc < 2; ++kc)
      qf[qg][kc] = *reinterpret_cast<const bf16x8*>(
          Q + base + (size_t)(qt * 256 + w * 64 + qg * 16 + lq) * 64 + kc * 32 + quad * 8);

  // staging: slot = r*256+t; row = slot>>3; source chunk = (slot&7) ^ s(row)
  int ko[2], vo[2];
#pragma unroll
  for (int r = 0; r < 2; ++r) {
    const int slot = r * 256 + t;
    const int row = slot >> 3;
    const int sr = (row & 3) | (((row >> 3) & 1) << 2);
    const int cl = (slot & 7) ^ sr;
    ko[r] = row * 64 + cl * 8;     // K: [key][64]
    vo[r] = row * 2048 + cl * 8;   // Vt: [d][2048]
  }

  f32x4 O[4][4];
  f32x4 Lacc[4];
#pragma unroll
  for (int qg = 0; qg < 4; ++qg) {
    Lacc[qg] = f32x4{0.f, 0.f, 0.f, 0.f};
#pragma unroll
    for (int dg = 0; dg < 4; ++dg) O[qg][dg] = f32x4{0.f, 0.f, 0.f, 0.f};
  }

  const short oneb = (short)0x3F80;  // bf16 1.0
  const bf16x8 ones8 = {oneb, oneb, oneb, oneb, oneb, oneb, oneb, oneb};

  // prologue: stage tile 0 into buffer 0
  {
    const u16* kgp = K + base;
    const u16* vgp = Vt + base;
    async16(kgp + ko[0], &Ks[0][(w * 64) * 8]);
    async16(kgp + ko[1], &Ks[0][(256 + w * 64) * 8]);
    async16(vgp + vo[0], &Vs[0][(w * 64) * 8]);
    async16(vgp + vo[1], &Vs[0][(256 + w * 64) * 8]);
  }

  for (int kt = 0; kt < 32; ++kt) {
    const int cur = kt & 1;
    __syncthreads();  // drains DMA into buf[cur]; prior reads of buf[cur^1] done
    if (kt < 31) {
      const u16* kgp = K + base + (size_t)(kt + 1) * 4096;
      const u16* vgp = Vt + base + (size_t)(kt + 1) * 64;
      const int nb = cur ^ 1;
      async16(kgp + ko[0], &Ks[nb][(w * 64) * 8]);
      async16(kgp + ko[1], &Ks[nb][(256 + w * 64) * 8]);
      async16(vgp + vo[0], &Vs[nb][(w * 64) * 8]);
      async16(vgp + vo[1], &Vs[nb][(256 + w * 64) * 8]);
    }

#pragma unroll
    for (int half = 0; half < 2; ++half) {
      // permuted K rows: key = half*32 + (lq>>2)*8 + kg2*4 + (lq&3)
      const int rb = half * 32 + ((lq >> 2) << 3) + (lq & 3);
      bf16x8 kf[2][2];
#pragma unroll
      for (int kg2 = 0; kg2 < 2; ++kg2) {
        const int krow = rb + kg2 * 4;
        kf[kg2][0] = *reinterpret_cast<const bf16x8*>(
            &Ks[cur][krow * 64 + (quad ^ swk) * 8]);          // d chunk = quad
        kf[kg2][1] = *reinterpret_cast<const bf16x8*>(
            &Ks[cur][krow * 64 + ((quad + 4) ^ swk) * 8]);    // d chunk = quad+4
      }

      // V B-frags (16x16x32): B[k=key][n=d], keys half*32+quad*8..+7 contiguous
      bf16x8 vbf[4];
#pragma unroll
      for (int dg = 0; dg < 4; ++dg)
        vbf[dg] = *reinterpret_cast<const bf16x8*>(
            &Vs[cur][(dg * 16 + lq) * 64 + ((half * 4 + quad) ^ swv) * 8]);

#pragma unroll
      for (int qg = 0; qg < 4; ++qg) {
        // S^T[key][q] for the 32-key half: two sub-MFMAs x two d-chunks
        f32x4 z0 = {0.f, 0.f, 0.f, 0.f}, z1 = {0.f, 0.f, 0.f, 0.f};
        z0 = __builtin_amdgcn_mfma_f32_16x16x32_bf16(kf[0][0], qf[qg][0], z0, 0, 0, 0);
        z0 = __builtin_amdgcn_mfma_f32_16x16x32_bf16(kf[0][1], qf[qg][1], z0, 0, 0, 0);
        z1 = __builtin_amdgcn_mfma_f32_16x16x32_bf16(kf[1][0], qf[qg][0], z1, 0, 0, 0);
        z1 = __builtin_amdgcn_mfma_f32_16x16x32_bf16(kf[1][1], qf[qg][1], z1, 0, 0, 0);

        const float cf = cft[half][qg];
        const float p0 = fexp2(__builtin_fmaf(z0[0], cf, -MC));
        const float p1 = fexp2(__builtin_fmaf(z0[1], cf, -MC));
        const float p2 = fexp2(__builtin_fmaf(z0[2], cf, -MC));
        const float p3 = fexp2(__builtin_fmaf(z0[3], cf, -MC));
        const float p4 = fexp2(__builtin_fmaf(z1[0], cf, -MC));
        const float p5 = fexp2(__builtin_fmaf(z1[1], cf, -MC));
        const float p6 = fexp2(__builtin_fmaf(z1[2], cf, -MC));
        const float p7 = fexp2(__builtin_fmaf(z1[3], cf, -MC));

        u32x4 pk;
        pk.x = pk2bf(p0, p1);
        pk.y = pk2bf(p2, p3);
        pk.z = pk2bf(p4, p5);
        pk.w = pk2bf(p6, p7);
        const bf16x8 pa = __builtin_bit_cast(bf16x8, pk);

        // softmax denominator: C reg r = sum_k P[q=qg*16+quad*4+r][k]
        Lacc[qg] = __builtin_amdgcn_mfma_f32_16x16x32_bf16(pa, ones8, Lacc[qg], 0, 0, 0);
#pragma unroll
        for (int dg = 0; dg < 4; ++dg)
          O[qg][dg] = __builtin_amdgcn_mfma_f32_16x16x32_bf16(pa, vbf[dg], O[qg][dg], 0, 0, 0);
      }
    }
  }

  // epilogue: O C-layout: q = qg*16+quad*4+r (row), d = dg*16+lq (col);
  // Lacc has the matching row layout -- no cross-lane reduce needed.
#pragma unroll
  for (int qg = 0; qg < 4; ++qg) {
#pragma unroll
    for (int r = 0; r < 4; ++r) {
      const float iv = 1.f / Lacc[qg][r];
      const size_t trow = (size_t)(qt * 256 + w * 64 + qg * 16 + quad * 4 + r);
      float* op = out + ((size_t)b * 2048 + trow) * 1024 + h * 64 + lq;
#pragma unroll
      for (int dg = 0; dg < 4; ++dg) op[dg * 16] = O[qg][dg][r] * iv;
    }
  }
}

extern "C" void kernel_launch(void* const* d_in, const int* in_sizes, int n_in,
                              void* d_out, int out_size, void* d_ws, size_t ws_size,
                              hipStream_t stream) {
  (void)in_sizes; (void)n_in; (void)out_size; (void)ws_size;
  const float* x = (const float*)d_in[0];
  const float* Wq = (const float*)d_in[1];
  const float* Wk = (const float*)d_in[2];
  const float* Wv = (const float*)d_in[3];
  const float* wip = (const float*)d_in[4];
  float* out = (float*)d_out;

  u16* xb = (u16*)d_ws;
  u16* wb = xb + 8388608;
  u16* qb = wb + 3145728;
  u16* kb = qb + 8388608;
  u16* vb = kb + 8388608;   // holds V^T [B][H][64][2048]

  cvt_all<<<11264, 256, 0, stream>>>(x, Wq, Wk, Wv, xb, wb);
  qkv_gemm<<<dim3(64, 8, 3), 256, 0, stream>>>(xb, wb, qb);
  palace_attn<<<dim3(64, 8, 1), 256, 0, stream>>>(qb, kb, vb, out, wip);
}

// Round 7
// 216.882 us; speedup vs baseline: 1.2875x; 1.1511x over previous
//
#include <hip/hip_runtime.h>

typedef unsigned short u16;
typedef unsigned int u32;
typedef short bf16x8 __attribute__((ext_vector_type(8)));
typedef float f32x4 __attribute__((ext_vector_type(4)));
typedef u32 u32x4 __attribute__((ext_vector_type(4)));

#define AS_GLOBAL __attribute__((address_space(1)))
#define AS_LDS __attribute__((address_space(3)))

__device__ __forceinline__ void async16(const void* g, void* l) {
  __builtin_amdgcn_global_load_lds((const AS_GLOBAL u32*)g, (AS_LDS u32*)l, 16, 0, 0);
}

__device__ __forceinline__ u16 f2bf(float f) {
  u32 u = __builtin_bit_cast(u32, f);
  u += 0x7FFFu + ((u >> 16) & 1u);   // RNE
  return (u16)(u >> 16);
}

__device__ __forceinline__ u32 pk2bf(float lo, float hi) {
  return __builtin_amdgcn_perm(__builtin_bit_cast(u32, hi),
                               __builtin_bit_cast(u32, lo), 0x07060302u);
}

__device__ __forceinline__ float fexp2(float x) {
#if __has_builtin(__builtin_amdgcn_exp2f)
  return __builtin_amdgcn_exp2f(x);
#else
  return exp2f(x);
#endif
}

// ---------------- Pass A: all four f32 -> bf16 converts in one launch ----------------
__global__ __launch_bounds__(256) void cvt_all(const float* __restrict__ x,
                                               const float* __restrict__ wq,
                                               const float* __restrict__ wk,
                                               const float* __restrict__ wv,
                                               u16* __restrict__ xb,
                                               u16* __restrict__ wb) {
  const int blk = blockIdx.x;
  const float* src;
  u16* dst;
  int i;
  if (blk < 8192) {
    src = x; dst = xb; i = blk * 256 + threadIdx.x;
  } else if (blk < 9216) {
    src = wq; dst = wb; i = (blk - 8192) * 256 + threadIdx.x;
  } else if (blk < 10240) {
    src = wk; dst = wb + 1048576; i = (blk - 9216) * 256 + threadIdx.x;
  } else {
    src = wv; dst = wb + 2097152; i = (blk - 10240) * 256 + threadIdx.x;
  }
  float4 f = reinterpret_cast<const float4*>(src)[i];
  ushort4 o;
  o.x = f2bf(f.x); o.y = f2bf(f.y); o.z = f2bf(f.z); o.w = f2bf(f.w);
  reinterpret_cast<ushort4*>(dst)[i] = o;
}

// ---------------- Pass B: QKV projection GEMM (C = X * W^T) ----------------
// K-loop: EXACT round-3 measured configuration (88 us): 256 thr, 2x2 waves of
// 64x64, BK=64, double-buffered LDS, one __syncthreads per k-tile with DMA for
// tile t+1 issued right after, conflict-free chunk-XOR swizzle (verified 0
// conflicts). Staging-side levers are exonerated (r2/r3/r6: conflicts,
// barrier count, DMA depth all null).
// NEW (round-7 experiment): wide-store epilogue. The old epilogue issued 64
// scalar u16 global stores per thread (4-16 cache lines touched per instr;
// V-transpose worst). Now: stage C into LDS (reusing the staging buffers
// after a barrier; wave-private [64][80]-stride region, ~2-way banks), then
// 8 x global_store_dwordx4 per thread:
//   z!=2: each wave's 64x64 C tile is ONE contiguous 8KB global region
//         ([B][H][T][64], t contiguous) -> 1KB per store instr, perfect.
//   z==2: 8 x 128B segments per instr (d-major [B][H][64][T]) vs 16 scattered
//         lines before.
// grid: x = m-tile (64), y = n-tile (8), z = matrix (3)
// z=0 (Q), z=1 (K): out [B][H][T][64]; z=2 (V): out TRANSPOSED [B][H][64][T]
__global__ __launch_bounds__(256, 2) void qkv_gemm(const u16* __restrict__ X,
                                                   const u16* __restrict__ W,
                                                   u16* __restrict__ O) {
  const int z = blockIdx.z;
  const u16* Wz = W + (size_t)z * (1024 * 1024);
  u16* Oz = O + (size_t)z * (8192 * 1024);

  // unified 64KB: SMEM[0..1] = A dbuf, SMEM[2..3] = B dbuf; epilogue reuses
  // SMEM[w] as wave-private staging (8192 u16 each >= 64*80).
  __shared__ __align__(16) u16 SMEM[4][8192];

  const int t = threadIdx.x;
  const int lane = t & 63, w = t >> 6, quad = lane >> 4, lq = lane & 15;
  const int wm = (w >> 1) * 64, wn = (w & 1) * 64;
  const int sw = lq & 7;
  const size_t m0 = (size_t)blockIdx.x * 128;
  const int n0 = blockIdx.y * 128;

  // staging source offsets (u16 units): slot -> (row, pre-swizzled chunk)
  int off[4];
#pragma unroll
  for (int j = 0; j < 4; ++j) {
    const int s = j * 256 + t, row = s >> 3, c = (s & 7) ^ (row & 7);
    off[j] = row * 1024 + c * 8;
  }
  const u16* gA = X + m0 * 1024;
  const u16* gB = Wz + (size_t)n0 * 1024;

  f32x4 acc[4][4];
#pragma unroll
  for (int i = 0; i < 4; ++i)
#pragma unroll
    for (int j = 0; j < 4; ++j) acc[i][j] = f32x4{0.f, 0.f, 0.f, 0.f};

  // 8 gload_lds(16B)/thread stages one 128x64 A panel + 128x64 B panel
  auto stage = [&](int kt, int nb) {
    const u16* ga = gA + kt * 64;
    const u16* gb = gB + kt * 64;
#pragma unroll
    for (int j = 0; j < 4; ++j)
      async16(ga + off[j], &SMEM[nb][(j * 256 + t) * 8]);
#pragma unroll
    for (int j = 0; j < 4; ++j)
      async16(gb + off[j], &SMEM[2 + nb][(j * 256 + t) * 8]);
  };

  // prologue: stage tile 0 into buffer 0
  stage(0, 0);

  for (int kt = 0; kt < 16; ++kt) {
    const int cur = kt & 1;
    __syncthreads();                    // tile kt resident; buf[cur^1] free
    if (kt < 15) stage(kt + 1, cur ^ 1);

    bf16x8 Af[4][2], Bf[4][2];
#pragma unroll
    for (int i = 0; i < 4; ++i)
#pragma unroll
      for (int ks = 0; ks < 2; ++ks) {
        Af[i][ks] = *reinterpret_cast<const bf16x8*>(
            &SMEM[cur][(wm + i * 16 + lq) * 64 + ((ks * 4 + quad) ^ sw) * 8]);
        Bf[i][ks] = *reinterpret_cast<const bf16x8*>(
            &SMEM[2 + cur][(wn + i * 16 + lq) * 64 + ((ks * 4 + quad) ^ sw) * 8]);
      }
#pragma unroll
    for (int i = 0; i < 4; ++i)
#pragma unroll
      for (int j = 0; j < 4; ++j) {
        acc[i][j] = __builtin_amdgcn_mfma_f32_16x16x32_bf16(Af[i][0], Bf[j][0], acc[i][j], 0, 0, 0);
        acc[i][j] = __builtin_amdgcn_mfma_f32_16x16x32_bf16(Af[i][1], Bf[j][1], acc[i][j], 0, 0, 0);
      }
  }

  // ---- wide-store epilogue ----
  __syncthreads();                      // all LDS reads of the main loop done
  u16* ep = &SMEM[w][0];                // wave-private region, layout [64][80]
  if (z != 2) {
    // LDS row = local m (0..63), col = local n (0..63)
#pragma unroll
    for (int i = 0; i < 4; ++i)
#pragma unroll
      for (int j = 0; j < 4; ++j)
#pragma unroll
        for (int r = 0; r < 4; ++r)
          ep[(i * 16 + quad * 4 + r) * 80 + j * 16 + lq] = f2bf(acc[i][j][r]);
  } else {
    // transposed: LDS row = local n (=d), col = local m (=t)
#pragma unroll
    for (int i = 0; i < 4; ++i)
#pragma unroll
      for (int j = 0; j < 4; ++j)
#pragma unroll
        for (int r = 0; r < 4; ++r)
          ep[(j * 16 + lq) * 80 + i * 16 + quad * 4 + r] = f2bf(acc[i][j][r]);
  }
  asm volatile("s_waitcnt lgkmcnt(0)" ::: "memory");  // own-wave writes visible

  const int r8 = lane >> 3, c8 = lane & 7;            // 8 rows x 8 chunks
  const size_t ms = m0 + wm;
  const size_t bb = ms >> 11, tt0 = ms & 2047;
  const int hh = (n0 + wn) >> 6;
  if (z != 2) {
    // wave tile = contiguous 8KB at ((bb*16+hh)*2048 + tt0)*64
    u16* gbase = Oz + ((bb * 16 + hh) * 2048 + tt0) * 64;
#pragma unroll
    for (int kq = 0; kq < 8; ++kq) {
      const int row = kq * 8 + r8;
      bf16x8 v = *reinterpret_cast<const bf16x8*>(&ep[row * 80 + c8 * 8]);
      *reinterpret_cast<bf16x8*>(&gbase[(size_t)row * 64 + c8 * 8]) = v;
    }
  } else {
    // wave tile = 64 rows (d) of 128B at stride 4KB
    u16* gbase = Oz + ((size_t)(bb * 16 + hh) * 64) * 2048 + tt0;
#pragma unroll
    for (int kq = 0; kq < 8; ++kq) {
      const int row = kq * 8 + r8;
      bf16x8 v = *reinterpret_cast<const bf16x8*>(&ep[row * 80 + c8 * 8]);
      *reinterpret_cast<bf16x8*>(&gbase[(size_t)row * 2048 + c8 * 8]) = v;
    }
  }
}

// ---------------- Pass C: flash attention, S^T-form, full-rate 16x16x32 PV ----------------
// ROUND-3 PROVEN VERSION, UNCHANGED.
// grid: x = b*16+h (64), y = q-tile (8). Block = 4 waves, 64 q/wave.
// Key-permuted S^T: for the 32-key half `half`, sub-MFMA kg2 in {0,1} reads K row
//   key(m) = half*32 + (m>>2)*8 + kg2*4 + (m&3)   (m = A-frag row = lq)
// so the S^T C-output gives each lane its 8 P values at keys quad*8+{0..7} ==
// the 16x16x32 A-frag layout. PV runs at full 2xK MFMA rate; V B-frag is one
// contiguous bf16x8 per dg. Row-sum via mfma(pa, ones, Lacc): C reg r = lsum
// for q = qg*16+quad*4+r (same layout as O rows, no cross-lane reduce).
// LDS swizzle: position = chunk ^ s(row), s(row) = (row&3) | (((row>>3)&1)<<2).
__global__ __launch_bounds__(256, 2) void palace_attn(const u16* __restrict__ Q,
                                                      const u16* __restrict__ K,
                                                      const u16* __restrict__ Vt,
                                                      float* __restrict__ out,
                                                      const float* __restrict__ wptr) {
  const int bh = blockIdx.x, qt = blockIdx.y;
  const int h = bh & 15, b = bh >> 4;
  const size_t base = (size_t)bh * (2048 * 64);

  __shared__ __align__(16) u16 Ks[2][64 * 64];   // [key][d], swizzled 16B chunks
  __shared__ __align__(16) u16 Vs[2][64 * 64];   // [d][key], swizzled 16B chunks

  const int t = threadIdx.x;
  const int w = t >> 6, lane = t & 63, quad = lane >> 4, lq = lane & 15;
  const int lq3 = lq >> 3;
  const int swk = (lq & 3) | (((lq >> 2) & 1) << 2);  // s(row) for permuted K rows
  const int swv = (lq & 3) | (lq3 << 2);              // s(d) for V rows d=dg*16+lq
  const float sig = 1.f / (1.f + __expf(-wptr[0]));
  const float Ci = 0.125f * 1.44269504f;   // intra coeff (scale * log2 e)
  const float Co = Ci * sig;               // inter coeff
  const float MC = 14.4269504f;            // fixed softmax offset: 10 * log2 e

  // palace mask: q block (mod 64) = qg*2+lq3; key block = half*4+quad (uniform
  // over all 8 keys a lane owns, thanks to the key permutation).
  float cft[2][4];
#pragma unroll
  for (int half = 0; half < 2; ++half)
#pragma unroll
    for (int qg = 0; qg < 4; ++qg)
      cft[half][qg] = (half * 4 + quad == qg * 2 + lq3) ? Ci : Co;

  // Q B-frags (16x16x32): B[k=d][n=q]
  bf16x8 qf[4][2];
#pragma unroll
  for (int qg = 0; qg < 4; ++qg)
#pragma unroll
    for (int kc = 0; kc < 2; ++kc)
      qf[qg][kc] = *reinterpret_cast<const bf16x8*>(
          Q + base + (size_t)(qt * 256 + w * 64 + qg * 16 + lq) * 64 + kc * 32 + quad * 8);

  // staging: slot = r*256+t; row = slot>>3; source chunk = (slot&7) ^ s(row)
  int ko[2], vo[2];
#pragma unroll
  for (int r = 0; r < 2; ++r) {
    const int slot = r * 256 + t;
    const int row = slot >> 3;
    const int sr = (row & 3) | (((row >> 3) & 1) << 2);
    const int cl = (slot & 7) ^ sr;
    ko[r] = row * 64 + cl * 8;     // K: [key][64]
    vo[r] = row * 2048 + cl * 8;   // Vt: [d][2048]
  }

  f32x4 O[4][4];
  f32x4 Lacc[4];
#pragma unroll
  for (int qg = 0; qg < 4; ++qg) {
    Lacc[qg] = f32x4{0.f, 0.f, 0.f, 0.f};
#pragma unroll
    for (int dg = 0; dg < 4; ++dg) O[qg][dg] = f32x4{0.f, 0.f, 0.f, 0.f};
  }

  const short oneb = (short)0x3F80;  // bf16 1.0
  const bf16x8 ones8 = {oneb, oneb, oneb, oneb, oneb, oneb, oneb, oneb};

  // prologue: stage tile 0 into buffer 0
  {
    const u16* kgp = K + base;
    const u16* vgp = Vt + base;
    async16(kgp + ko[0], &Ks[0][(w * 64) * 8]);
    async16(kgp + ko[1], &Ks[0][(256 + w * 64) * 8]);
    async16(vgp + vo[0], &Vs[0][(w * 64) * 8]);
    async16(vgp + vo[1], &Vs[0][(256 + w * 64) * 8]);
  }

  for (int kt = 0; kt < 32; ++kt) {
    const int cur = kt & 1;
    __syncthreads();  // drains DMA into buf[cur]; prior reads of buf[cur^1] done
    if (kt < 31) {
      const u16* kgp = K + base + (size_t)(kt + 1) * 4096;
      const u16* vgp = Vt + base + (size_t)(kt + 1) * 64;
      const int nb = cur ^ 1;
      async16(kgp + ko[0], &Ks[nb][(w * 64) * 8]);
      async16(kgp + ko[1], &Ks[nb][(256 + w * 64) * 8]);
      async16(vgp + vo[0], &Vs[nb][(w * 64) * 8]);
      async16(vgp + vo[1], &Vs[nb][(256 + w * 64) * 8]);
    }

#pragma unroll
    for (int half = 0; half < 2; ++half) {
      // permuted K rows: key = half*32 + (lq>>2)*8 + kg2*4 + (lq&3)
      const int rb = half * 32 + ((lq >> 2) << 3) + (lq & 3);
      bf16x8 kf[2][2];
#pragma unroll
      for (int kg2 = 0; kg2 < 2; ++kg2) {
        const int krow = rb + kg2 * 4;
        kf[kg2][0] = *reinterpret_cast<const bf16x8*>(
            &Ks[cur][krow * 64 + (quad ^ swk) * 8]);          // d chunk = quad
        kf[kg2][1] = *reinterpret_cast<const bf16x8*>(
            &Ks[cur][krow * 64 + ((quad + 4) ^ swk) * 8]);    // d chunk = quad+4
      }

      // V B-frags (16x16x32): B[k=key][n=d], keys half*32+quad*8..+7 contiguous
      bf16x8 vbf[4];
#pragma unroll
      for (int dg = 0; dg < 4; ++dg)
        vbf[dg] = *reinterpret_cast<const bf16x8*>(
            &Vs[cur][(dg * 16 + lq) * 64 + ((half * 4 + quad) ^ swv) * 8]);

#pragma unroll
      for (int qg = 0; qg < 4; ++qg) {
        // S^T[key][q] for the 32-key half: two sub-MFMAs x two d-chunks
        f32x4 z0 = {0.f, 0.f, 0.f, 0.f}, z1 = {0.f, 0.f, 0.f, 0.f};
        z0 = __builtin_amdgcn_mfma_f32_16x16x32_bf16(kf[0][0], qf[qg][0], z0, 0, 0, 0);
        z0 = __builtin_amdgcn_mfma_f32_16x16x32_bf16(kf[0][1], qf[qg][1], z0, 0, 0, 0);
        z1 = __builtin_amdgcn_mfma_f32_16x16x32_bf16(kf[1][0], qf[qg][0], z1, 0, 0, 0);
        z1 = __builtin_amdgcn_mfma_f32_16x16x32_bf16(kf[1][1], qf[qg][1], z1, 0, 0, 0);

        const float cf = cft[half][qg];
        const float p0 = fexp2(__builtin_fmaf(z0[0], cf, -MC));
        const float p1 = fexp2(__builtin_fmaf(z0[1], cf, -MC));
        const float p2 = fexp2(__builtin_fmaf(z0[2], cf, -MC));
        const float p3 = fexp2(__builtin_fmaf(z0[3], cf, -MC));
        const float p4 = fexp2(__builtin_fmaf(z1[0], cf, -MC));
        const float p5 = fexp2(__builtin_fmaf(z1[1], cf, -MC));
        const float p6 = fexp2(__builtin_fmaf(z1[2], cf, -MC));
        const float p7 = fexp2(__builtin_fmaf(z1[3], cf, -MC));

        u32x4 pk;
        pk.x = pk2bf(p0, p1);
        pk.y = pk2bf(p2, p3);
        pk.z = pk2bf(p4, p5);
        pk.w = pk2bf(p6, p7);
        const bf16x8 pa = __builtin_bit_cast(bf16x8, pk);

        // softmax denominator: C reg r = sum_k P[q=qg*16+quad*4+r][k]
        Lacc[qg] = __builtin_amdgcn_mfma_f32_16x16x32_bf16(pa, ones8, Lacc[qg], 0, 0, 0);
#pragma unroll
        for (int dg = 0; dg < 4; ++dg)
          O[qg][dg] = __builtin_amdgcn_mfma_f32_16x16x32_bf16(pa, vbf[dg], O[qg][dg], 0, 0, 0);
      }
    }
  }

  // epilogue: O C-layout: q = qg*16+quad*4+r (row), d = dg*16+lq (col);
  // Lacc has the matching row layout -- no cross-lane reduce needed.
#pragma unroll
  for (int qg = 0; qg < 4; ++qg) {
#pragma unroll
    for (int r = 0; r < 4; ++r) {
      const float iv = 1.f / Lacc[qg][r];
      const size_t trow = (size_t)(qt * 256 + w * 64 + qg * 16 + quad * 4 + r);
      float* op = out + ((size_t)b * 2048 + trow) * 1024 + h * 64 + lq;
#pragma unroll
      for (int dg = 0; dg < 4; ++dg) op[dg * 16] = O[qg][dg][r] * iv;
    }
  }
}

extern "C" void kernel_launch(void* const* d_in, const int* in_sizes, int n_in,
                              void* d_out, int out_size, void* d_ws, size_t ws_size,
                              hipStream_t stream) {
  (void)in_sizes; (void)n_in; (void)out_size; (void)ws_size;
  const float* x = (const float*)d_in[0];
  const float* Wq = (const float*)d_in[1];
  const float* Wk = (const float*)d_in[2];
  const float* Wv = (const float*)d_in[3];
  const float* wip = (const float*)d_in[4];
  float* out = (float*)d_out;

  u16* xb = (u16*)d_ws;
  u16* wb = xb + 8388608;
  u16* qb = wb + 3145728;
  u16* kb = qb + 8388608;
  u16* vb = kb + 8388608;   // holds V^T [B][H][64][2048]

  cvt_all<<<11264, 256, 0, stream>>>(x, Wq, Wk, Wv, xb, wb);
  qkv_gemm<<<dim3(64, 8, 3), 256, 0, stream>>>(xb, wb, qb);
  palace_attn<<<dim3(64, 8, 1), 256, 0, stream>>>(qb, kb, vb, out, wip);
}

// Round 8
// 211.657 us; speedup vs baseline: 1.3193x; 1.0247x over previous
//
#include <hip/hip_runtime.h>

typedef unsigned short u16;
typedef unsigned int u32;
typedef short bf16x8 __attribute__((ext_vector_type(8)));
typedef float f32x4 __attribute__((ext_vector_type(4)));
typedef u32 u32x4 __attribute__((ext_vector_type(4)));

#define AS_GLOBAL __attribute__((address_space(1)))
#define AS_LDS __attribute__((address_space(3)))

__device__ __forceinline__ void async16(const void* g, void* l) {
  __builtin_amdgcn_global_load_lds((const AS_GLOBAL u32*)g, (AS_LDS u32*)l, 16, 0, 0);
}

__device__ __forceinline__ u16 f2bf(float f) {
  u32 u = __builtin_bit_cast(u32, f);
  u += 0x7FFFu + ((u >> 16) & 1u);   // RNE
  return (u16)(u >> 16);
}

__device__ __forceinline__ u32 pk2bf(float lo, float hi) {
  return __builtin_amdgcn_perm(__builtin_bit_cast(u32, hi),
                               __builtin_bit_cast(u32, lo), 0x07060302u);
}

__device__ __forceinline__ float fexp2(float x) {
#if __has_builtin(__builtin_amdgcn_exp2f)
  return __builtin_amdgcn_exp2f(x);
#else
  return exp2f(x);
#endif
}

// ---------------- Pass A: all four f32 -> bf16 converts in one launch ----------------
__global__ __launch_bounds__(256) void cvt_all(const float* __restrict__ x,
                                               const float* __restrict__ wq,
                                               const float* __restrict__ wk,
                                               const float* __restrict__ wv,
                                               u16* __restrict__ xb,
                                               u16* __restrict__ wb) {
  const int blk = blockIdx.x;
  const float* src;
  u16* dst;
  int i;
  if (blk < 8192) {
    src = x; dst = xb; i = blk * 256 + threadIdx.x;
  } else if (blk < 9216) {
    src = wq; dst = wb; i = (blk - 8192) * 256 + threadIdx.x;
  } else if (blk < 10240) {
    src = wk; dst = wb + 1048576; i = (blk - 9216) * 256 + threadIdx.x;
  } else {
    src = wv; dst = wb + 2097152; i = (blk - 10240) * 256 + threadIdx.x;
  }
  float4 f = reinterpret_cast<const float4*>(src)[i];
  ushort4 o;
  o.x = f2bf(f.x); o.y = f2bf(f.y); o.z = f2bf(f.z); o.w = f2bf(f.w);
  reinterpret_cast<ushort4*>(dst)[i] = o;
}

// ---------------- Pass B: QKV projection GEMM (C = X * W^T) ----------------
// ROUND-7 PROVEN VERSION, UNCHANGED (wide-store epilogue win: 88 -> ~60 us).
// K-loop: 256 thr, 2x2 waves of 64x64, BK=64, double-buffered LDS, one
// __syncthreads per k-tile, conflict-free chunk-XOR swizzle. Epilogue stages
// C through LDS and emits 8 x global_store_dwordx4 per thread.
// grid: x = m-tile (64), y = n-tile (8), z = matrix (3)
// z=0 (Q), z=1 (K): out [B][H][T][64]; z=2 (V): out TRANSPOSED [B][H][64][T]
__global__ __launch_bounds__(256, 2) void qkv_gemm(const u16* __restrict__ X,
                                                   const u16* __restrict__ W,
                                                   u16* __restrict__ O) {
  const int z = blockIdx.z;
  const u16* Wz = W + (size_t)z * (1024 * 1024);
  u16* Oz = O + (size_t)z * (8192 * 1024);

  // unified 64KB: SMEM[0..1] = A dbuf, SMEM[2..3] = B dbuf; epilogue reuses
  // SMEM[w] as wave-private staging (8192 u16 each >= 64*80).
  __shared__ __align__(16) u16 SMEM[4][8192];

  const int t = threadIdx.x;
  const int lane = t & 63, w = t >> 6, quad = lane >> 4, lq = lane & 15;
  const int wm = (w >> 1) * 64, wn = (w & 1) * 64;
  const int sw = lq & 7;
  const size_t m0 = (size_t)blockIdx.x * 128;
  const int n0 = blockIdx.y * 128;

  // staging source offsets (u16 units): slot -> (row, pre-swizzled chunk)
  int off[4];
#pragma unroll
  for (int j = 0; j < 4; ++j) {
    const int s = j * 256 + t, row = s >> 3, c = (s & 7) ^ (row & 7);
    off[j] = row * 1024 + c * 8;
  }
  const u16* gA = X + m0 * 1024;
  const u16* gB = Wz + (size_t)n0 * 1024;

  f32x4 acc[4][4];
#pragma unroll
  for (int i = 0; i < 4; ++i)
#pragma unroll
    for (int j = 0; j < 4; ++j) acc[i][j] = f32x4{0.f, 0.f, 0.f, 0.f};

  // 8 gload_lds(16B)/thread stages one 128x64 A panel + 128x64 B panel
  auto stage = [&](int kt, int nb) {
    const u16* ga = gA + kt * 64;
    const u16* gb = gB + kt * 64;
#pragma unroll
    for (int j = 0; j < 4; ++j)
      async16(ga + off[j], &SMEM[nb][(j * 256 + t) * 8]);
#pragma unroll
    for (int j = 0; j < 4; ++j)
      async16(gb + off[j], &SMEM[2 + nb][(j * 256 + t) * 8]);
  };

  // prologue: stage tile 0 into buffer 0
  stage(0, 0);

  for (int kt = 0; kt < 16; ++kt) {
    const int cur = kt & 1;
    __syncthreads();                    // tile kt resident; buf[cur^1] free
    if (kt < 15) stage(kt + 1, cur ^ 1);

    bf16x8 Af[4][2], Bf[4][2];
#pragma unroll
    for (int i = 0; i < 4; ++i)
#pragma unroll
      for (int ks = 0; ks < 2; ++ks) {
        Af[i][ks] = *reinterpret_cast<const bf16x8*>(
            &SMEM[cur][(wm + i * 16 + lq) * 64 + ((ks * 4 + quad) ^ sw) * 8]);
        Bf[i][ks] = *reinterpret_cast<const bf16x8*>(
            &SMEM[2 + cur][(wn + i * 16 + lq) * 64 + ((ks * 4 + quad) ^ sw) * 8]);
      }
#pragma unroll
    for (int i = 0; i < 4; ++i)
#pragma unroll
      for (int j = 0; j < 4; ++j) {
        acc[i][j] = __builtin_amdgcn_mfma_f32_16x16x32_bf16(Af[i][0], Bf[j][0], acc[i][j], 0, 0, 0);
        acc[i][j] = __builtin_amdgcn_mfma_f32_16x16x32_bf16(Af[i][1], Bf[j][1], acc[i][j], 0, 0, 0);
      }
  }

  // ---- wide-store epilogue ----
  __syncthreads();                      // all LDS reads of the main loop done
  u16* ep = &SMEM[w][0];                // wave-private region, layout [64][80]
  if (z != 2) {
    // LDS row = local m (0..63), col = local n (0..63)
#pragma unroll
    for (int i = 0; i < 4; ++i)
#pragma unroll
      for (int j = 0; j < 4; ++j)
#pragma unroll
        for (int r = 0; r < 4; ++r)
          ep[(i * 16 + quad * 4 + r) * 80 + j * 16 + lq] = f2bf(acc[i][j][r]);
  } else {
    // transposed: LDS row = local n (=d), col = local m (=t)
#pragma unroll
    for (int i = 0; i < 4; ++i)
#pragma unroll
      for (int j = 0; j < 4; ++j)
#pragma unroll
        for (int r = 0; r < 4; ++r)
          ep[(j * 16 + lq) * 80 + i * 16 + quad * 4 + r] = f2bf(acc[i][j][r]);
  }
  asm volatile("s_waitcnt lgkmcnt(0)" ::: "memory");  // own-wave writes visible

  const int r8 = lane >> 3, c8 = lane & 7;            // 8 rows x 8 chunks
  const size_t ms = m0 + wm;
  const size_t bb = ms >> 11, tt0 = ms & 2047;
  const int hh = (n0 + wn) >> 6;
  if (z != 2) {
    // wave tile = contiguous 8KB at ((bb*16+hh)*2048 + tt0)*64
    u16* gbase = Oz + ((bb * 16 + hh) * 2048 + tt0) * 64;
#pragma unroll
    for (int kq = 0; kq < 8; ++kq) {
      const int row = kq * 8 + r8;
      bf16x8 v = *reinterpret_cast<const bf16x8*>(&ep[row * 80 + c8 * 8]);
      *reinterpret_cast<bf16x8*>(&gbase[(size_t)row * 64 + c8 * 8]) = v;
    }
  } else {
    // wave tile = 64 rows (d) of 128B at stride 4KB
    u16* gbase = Oz + ((size_t)(bb * 16 + hh) * 64) * 2048 + tt0;
#pragma unroll
    for (int kq = 0; kq < 8; ++kq) {
      const int row = kq * 8 + r8;
      bf16x8 v = *reinterpret_cast<const bf16x8*>(&ep[row * 80 + c8 * 8]);
      *reinterpret_cast<bf16x8*>(&gbase[(size_t)row * 2048 + c8 * 8]) = v;
    }
  }
}

// ---------------- Pass C: flash attention, S^T-form, full-rate 16x16x32 PV ----------------
// Round-8 experiment: 8 WAVES/BLOCK (512 thr), 32 q-rows/wave (qg: 4 -> 2).
// Same 256-q tile, same grid (64 x 8 = 512 blocks) -> still 2 blocks/CU but
// now 16 waves/CU (was 8). K/V LDS tiles are shared by all waves, so per-CU
// DMA + LDS footprint UNCHANGED; per-wave state halves (VGPR ~120 -> ~90).
// Pure occupancy/TLP lever against the serial QK->softmax->PV chain
// (round-7 counters: MfmaUtil 38 + VALUBusy 44, occupancy only 17%).
//
// Key-permuted S^T (unchanged): for 32-key half `half`, sub-MFMA kg2 reads
// K row key(m) = half*32 + (m>>2)*8 + kg2*4 + (m&3), so each lane's 8 P
// values sit at keys quad*8+{0..7} == the 16x16x32 A-frag layout. PV at full
// 2xK rate; V B-frag one contiguous bf16x8 per dg. Row-sum via
// mfma(pa, ones, Lacc). Palace mask: q-slot = (w&1)*4 + qg*2 + (lq>>3)
// (q = qt*256 + w*32 + qg*16 + lq); key-slot = half*4 + quad, uniform over
// the lane's 8 keys.
// LDS swizzle: position = chunk ^ s(row), s(row) = (row&3) | (((row>>3)&1)<<2).
__global__ __launch_bounds__(512, 4) void palace_attn(const u16* __restrict__ Q,
                                                      const u16* __restrict__ K,
                                                      const u16* __restrict__ Vt,
                                                      float* __restrict__ out,
                                                      const float* __restrict__ wptr) {
  const int bh = blockIdx.x, qt = blockIdx.y;
  const int h = bh & 15, b = bh >> 4;
  const size_t base = (size_t)bh * (2048 * 64);

  __shared__ __align__(16) u16 Ks[2][64 * 64];   // [key][d], swizzled 16B chunks
  __shared__ __align__(16) u16 Vs[2][64 * 64];   // [d][key], swizzled 16B chunks

  const int t = threadIdx.x;
  const int w = t >> 6, lane = t & 63, quad = lane >> 4, lq = lane & 15;
  const int lq3 = lq >> 3;
  const int swk = (lq & 3) | (((lq >> 2) & 1) << 2);  // s(row) for permuted K rows
  const int swv = (lq & 3) | (lq3 << 2);              // s(d) for V rows d=dg*16+lq
  const float sig = 1.f / (1.f + __expf(-wptr[0]));
  const float Ci = 0.125f * 1.44269504f;   // intra coeff (scale * log2 e)
  const float Co = Ci * sig;               // inter coeff
  const float MC = 14.4269504f;            // fixed softmax offset: 10 * log2 e

  // palace mask: q-slot = (w&1)*4 + qg*2 + lq3; key-slot = half*4 + quad
  const int qs0 = (w & 1) * 4;
  float cft[2][2];
#pragma unroll
  for (int half = 0; half < 2; ++half)
#pragma unroll
    for (int qg = 0; qg < 2; ++qg)
      cft[half][qg] = (half * 4 + quad == qs0 + qg * 2 + lq3) ? Ci : Co;

  // Q B-frags (16x16x32): B[k=d][n=q], q = qt*256 + w*32 + qg*16 + lq
  bf16x8 qf[2][2];
#pragma unroll
  for (int qg = 0; qg < 2; ++qg)
#pragma unroll
    for (int kc = 0; kc < 2; ++kc)
      qf[qg][kc] = *reinterpret_cast<const bf16x8*>(
          Q + base + (size_t)(qt * 256 + w * 32 + qg * 16 + lq) * 64 + kc * 32 + quad * 8);

  // staging: slot = t (512 threads cover 512 16B slots); row = slot>>3;
  // source chunk = (slot&7) ^ s(row)
  const int row_s = t >> 3;
  const int sr_s = (row_s & 3) | (((row_s >> 3) & 1) << 2);
  const int cl_s = (t & 7) ^ sr_s;
  const int ko = row_s * 64 + cl_s * 8;     // K: [key][64]
  const int vo = row_s * 2048 + cl_s * 8;   // Vt: [d][2048]

  f32x4 O[2][4];
  f32x4 Lacc[2];
#pragma unroll
  for (int qg = 0; qg < 2; ++qg) {
    Lacc[qg] = f32x4{0.f, 0.f, 0.f, 0.f};
#pragma unroll
    for (int dg = 0; dg < 4; ++dg) O[qg][dg] = f32x4{0.f, 0.f, 0.f, 0.f};
  }

  const short oneb = (short)0x3F80;  // bf16 1.0
  const bf16x8 ones8 = {oneb, oneb, oneb, oneb, oneb, oneb, oneb, oneb};

  // prologue: stage tile 0 into buffer 0 (1 K + 1 V load per thread)
  {
    const u16* kgp = K + base;
    const u16* vgp = Vt + base;
    async16(kgp + ko, &Ks[0][(w * 64) * 8]);
    async16(vgp + vo, &Vs[0][(w * 64) * 8]);
  }

  for (int kt = 0; kt < 32; ++kt) {
    const int cur = kt & 1;
    __syncthreads();  // drains DMA into buf[cur]; prior reads of buf[cur^1] done
    if (kt < 31) {
      const u16* kgp = K + base + (size_t)(kt + 1) * 4096;
      const u16* vgp = Vt + base + (size_t)(kt + 1) * 64;
      const int nb = cur ^ 1;
      async16(kgp + ko, &Ks[nb][(w * 64) * 8]);
      async16(vgp + vo, &Vs[nb][(w * 64) * 8]);
    }

#pragma unroll
    for (int half = 0; half < 2; ++half) {
      // permuted K rows: key = half*32 + (lq>>2)*8 + kg2*4 + (lq&3)
      const int rb = half * 32 + ((lq >> 2) << 3) + (lq & 3);
      bf16x8 kf[2][2];
#pragma unroll
      for (int kg2 = 0; kg2 < 2; ++kg2) {
        const int krow = rb + kg2 * 4;
        kf[kg2][0] = *reinterpret_cast<const bf16x8*>(
            &Ks[cur][krow * 64 + (quad ^ swk) * 8]);          // d chunk = quad
        kf[kg2][1] = *reinterpret_cast<const bf16x8*>(
            &Ks[cur][krow * 64 + ((quad + 4) ^ swk) * 8]);    // d chunk = quad+4
      }

      // V B-frags (16x16x32): B[k=key][n=d], keys half*32+quad*8..+7 contiguous
      bf16x8 vbf[4];
#pragma unroll
      for (int dg = 0; dg < 4; ++dg)
        vbf[dg] = *reinterpret_cast<const bf16x8*>(
            &Vs[cur][(dg * 16 + lq) * 64 + ((half * 4 + quad) ^ swv) * 8]);

#pragma unroll
      for (int qg = 0; qg < 2; ++qg) {
        // S^T[key][q] for the 32-key half: two sub-MFMAs x two d-chunks
        f32x4 z0 = {0.f, 0.f, 0.f, 0.f}, z1 = {0.f, 0.f, 0.f, 0.f};
        z0 = __builtin_amdgcn_mfma_f32_16x16x32_bf16(kf[0][0], qf[qg][0], z0, 0, 0, 0);
        z0 = __builtin_amdgcn_mfma_f32_16x16x32_bf16(kf[0][1], qf[qg][1], z0, 0, 0, 0);
        z1 = __builtin_amdgcn_mfma_f32_16x16x32_bf16(kf[1][0], qf[qg][0], z1, 0, 0, 0);
        z1 = __builtin_amdgcn_mfma_f32_16x16x32_bf16(kf[1][1], qf[qg][1], z1, 0, 0, 0);

        const float cf = cft[half][qg];
        const float p0 = fexp2(__builtin_fmaf(z0[0], cf, -MC));
        const float p1 = fexp2(__builtin_fmaf(z0[1], cf, -MC));
        const float p2 = fexp2(__builtin_fmaf(z0[2], cf, -MC));
        const float p3 = fexp2(__builtin_fmaf(z0[3], cf, -MC));
        const float p4 = fexp2(__builtin_fmaf(z1[0], cf, -MC));
        const float p5 = fexp2(__builtin_fmaf(z1[1], cf, -MC));
        const float p6 = fexp2(__builtin_fmaf(z1[2], cf, -MC));
        const float p7 = fexp2(__builtin_fmaf(z1[3], cf, -MC));

        u32x4 pk;
        pk.x = pk2bf(p0, p1);
        pk.y = pk2bf(p2, p3);
        pk.z = pk2bf(p4, p5);
        pk.w = pk2bf(p6, p7);
        const bf16x8 pa = __builtin_bit_cast(bf16x8, pk);

        // softmax denominator: C reg r = sum_k P[q=qg*16+quad*4+r][k]
        Lacc[qg] = __builtin_amdgcn_mfma_f32_16x16x32_bf16(pa, ones8, Lacc[qg], 0, 0, 0);
#pragma unroll
        for (int dg = 0; dg < 4; ++dg)
          O[qg][dg] = __builtin_amdgcn_mfma_f32_16x16x32_bf16(pa, vbf[dg], O[qg][dg], 0, 0, 0);
      }
    }
  }

  // epilogue: O C-layout: q = qg*16+quad*4+r (row), d = dg*16+lq (col);
  // Lacc has the matching row layout -- no cross-lane reduce needed.
#pragma unroll
  for (int qg = 0; qg < 2; ++qg) {
#pragma unroll
    for (int r = 0; r < 4; ++r) {
      const float iv = 1.f / Lacc[qg][r];
      const size_t trow = (size_t)(qt * 256 + w * 32 + qg * 16 + quad * 4 + r);
      float* op = out + ((size_t)b * 2048 + trow) * 1024 + h * 64 + lq;
#pragma unroll
      for (int dg = 0; dg < 4; ++dg) op[dg * 16] = O[qg][dg][r] * iv;
    }
  }
}

extern "C" void kernel_launch(void* const* d_in, const int* in_sizes, int n_in,
                              void* d_out, int out_size, void* d_ws, size_t ws_size,
                              hipStream_t stream) {
  (void)in_sizes; (void)n_in; (void)out_size; (void)ws_size;
  const float* x = (const float*)d_in[0];
  const float* Wq = (const float*)d_in[1];
  const float* Wk = (const float*)d_in[2];
  const float* Wv = (const float*)d_in[3];
  const float* wip = (const float*)d_in[4];
  float* out = (float*)d_out;

  u16* xb = (u16*)d_ws;
  u16* wb = xb + 8388608;
  u16* qb = wb + 3145728;
  u16* kb = qb + 8388608;
  u16* vb = kb + 8388608;   // holds V^T [B][H][64][2048]

  cvt_all<<<11264, 256, 0, stream>>>(x, Wq, Wk, Wv, xb, wb);
  qkv_gemm<<<dim3(64, 8, 3), 256, 0, stream>>>(xb, wb, qb);
  palace_attn<<<dim3(64, 8, 1), 512, 0, stream>>>(qb, kb, vb, out, wip);
}